// Round 22
// baseline (93.101 us; speedup 1.0000x reference)
//
#include <hip/hip_runtime.h>
#include <hip/hip_bf16.h>

typedef unsigned int uint32;
typedef __attribute__((ext_vector_type(8))) short    bf16x8;
typedef __attribute__((ext_vector_type(4))) float    f32x4;
typedef __attribute__((ext_vector_type(8))) _Float16 f16x8;
typedef __attribute__((ext_vector_type(4))) _Float16 f16x4;
typedef __attribute__((ext_vector_type(2))) _Float16 f16x2;

#define MFMA_BF(A, B, C) __builtin_amdgcn_mfma_f32_16x16x32_bf16(A, B, C, 0, 0, 0)
#define MFMA_F16(A, B, C) __builtin_amdgcn_mfma_f32_16x16x32_f16(A, B, C, 0, 0, 0)

union FragU { uint32 u[4]; bf16x8 v; };
union H8    { f16x2 h[4]; f16x8 v; };
union PkU   { _Float16 h[2]; uint32 u; };

// async global->LDS DMA, 16B/lane x 64 lanes = 1KB per issue (linear dest).
__device__ __forceinline__ void gl_lds16(const void* g, void* l) {
    __builtin_amdgcn_global_load_lds(
        (const __attribute__((address_space(1))) void*)g,
        (__attribute__((address_space(3))) void*)l, 16, 0, 0);
}

// 3-pass split (phase-1 z only): hi=trunc top16, lo=bf16(x-hi)
__device__ __forceinline__ void split8(f32x4 a, f32x4 b, bf16x8& hi, bf16x8& lo) {
    float e[8] = {a[0], a[1], a[2], a[3], b[0], b[1], b[2], b[3]};
    FragU H, L;
    #pragma unroll
    for (int q = 0; q < 4; ++q) {
        uint32 u0 = __float_as_uint(e[2*q]);
        uint32 u1 = __float_as_uint(e[2*q + 1]);
        uint32 h0 = u0 & 0xFFFF0000u;
        uint32 h1 = u1 & 0xFFFF0000u;
        float l0 = e[2*q]     - __uint_as_float(h0);
        float l1 = e[2*q + 1] - __uint_as_float(h1);
        H.u[q] = (h0 >> 16) | h1;
        L.u[q] = (__float_as_uint(l0) >> 16) | (__float_as_uint(l1) & 0xFFFF0000u);
    }
    hi = H.v; lo = L.v;
}

// ---- pre-kernel: |Wp| bf16 hi/lo; W2 fp16 LINEAR (r17-proven layout); tail
//      pack per d (448B): dw [0,16)=W1 f16x2, [16,32)=b1 f16x2, [32,64)=b2,
//      [64,96)=W3, [96]=b3.
__global__ __launch_bounds__(256) void split_weights(
    const float* __restrict__ Wp, const float* __restrict__ W2,
    const float* __restrict__ W1, const float* __restrict__ b1,
    const float* __restrict__ b2, const float* __restrict__ W3,
    const float* __restrict__ b3,
    __hip_bfloat16* __restrict__ wp_hi, __hip_bfloat16* __restrict__ wp_lo,
    _Float16* __restrict__ w2h, uint32* __restrict__ tailp)
{
    const int i = blockIdx.x * 256 + threadIdx.x;
    if (i < 128 * 64) {
        float x = fabsf(Wp[i]);
        __hip_bfloat16 h = __float2bfloat16(x);          // RNE
        wp_hi[i] = h;
        wp_lo[i] = __float2bfloat16(x - __bfloat162float(h));
    }
    if (i < 128 * 1024) {
        w2h[i] = (_Float16)W2[i];                        // RNE, linear
    }
    if (i < 128 * 112) {
        const int d = i / 112, s = i % 112;
        uint32 v = 0;
        if (s < 16) {
            PkU p; p.h[0] = (_Float16)W1[d*32 + 2*s];
                   p.h[1] = (_Float16)W1[d*32 + 2*s + 1];
            v = p.u;
        } else if (s < 32) {
            PkU p; p.h[0] = (_Float16)b1[d*32 + 2*(s-16)];
                   p.h[1] = (_Float16)b1[d*32 + 2*(s-16) + 1];
            v = p.u;
        } else if (s < 64)  v = __float_as_uint(b2[d*32 + s - 32]);
        else if (s < 96)    v = __float_as_uint(W3[d*32 + s - 64]);
        else if (s == 96)   v = __float_as_uint(b3[d]);
        tailp[d*112 + s] = v;
    }
}

// 1 wave per block: 64 samples x 32 features. TRIPLE-buffered weight DMA:
//   body j reads buf[j%3]; stages j+2 -> buf[(j+2)%3], which was consumed in
//   body j-1 whose ds_reads issued BEFORE this body's head-asm fence -> the
//   restage is race-free by construction (r18 re-staged the SAME buffer it
//   was reading; scheduler hoisting of the DMA above the ds_reads corrupted
//   weights -> absmax 102). vmcnt(3) at head retires stage(j) while keeping
//   stage(j+1) in flight (~1.5 bodies of latency cover, per T4).
__global__ __launch_bounds__(64, 4) void decoder_mfma(
    const float* __restrict__ z,
    const __hip_bfloat16* __restrict__ wp_hi, const __hip_bfloat16* __restrict__ wp_lo,
    const _Float16* __restrict__ w2h, const uint32* __restrict__ tailp,
    float* __restrict__ out)
{
    __shared__ __align__(16) _Float16 Y[64][36];    // 4608 B
    __shared__ __align__(16) _Float16 Wb[3][1024];  // 6144 B (W2 triple buffer)
    __shared__ __align__(16) uint32   Tb[3][256];   // 3072 B (tail; DMA lands 1KB)

    const int lane = threadIdx.x;    // 0..63
    const int l15  = lane & 15;
    const int lg   = lane >> 4;
    const int g     = blockIdx.x & 3;            // feature group [32g, 32g+32)
    const int dbase = g * 32;
    const int n0    = (blockIdx.x >> 2) * 64;    // sample tile

    auto stage = [&](int d, int b) {
        const _Float16* g0 = w2h + d*1024 + lane*8;
        gl_lds16(g0,       &Wb[b][0]);
        gl_lds16(g0 + 512, &Wb[b][512]);
        gl_lds16(tailp + d*112 + lane*4, &Tb[b][0]);
    };

    // ---- prologue: stage j=0 -> buf0, j=1 -> buf1 (hidden under phase 1) --
    stage(dbase,     0);
    stage(dbase + 1, 1);

    // ---------------- Phase 1: Y = z @ |Wp|^T (3-pass bf16) ---------------
    bf16x8 wh[2][2], wl[2][2];
    #pragma unroll
    for (int dt = 0; dt < 2; ++dt) {
        const int d = dbase + dt*16 + l15;
        #pragma unroll
        for (int kt = 0; kt < 2; ++kt) {
            const int off = d*64 + kt*32 + lg*8;
            wh[dt][kt] = *(const bf16x8*)(wp_hi + off);
            wl[dt][kt] = *(const bf16x8*)(wp_lo + off);
        }
    }
    #pragma unroll
    for (int nt = 0; nt < 4; ++nt) {
        bf16x8 zh[2], zl[2];
        #pragma unroll
        for (int kt = 0; kt < 2; ++kt) {
            const float* p = z + (size_t)(n0 + nt*16 + l15)*64 + kt*32 + lg*8;
            split8(*(const f32x4*)p, *(const f32x4*)(p + 4), zh[kt], zl[kt]);
        }
        #pragma unroll
        for (int dt = 0; dt < 2; ++dt) {
            f32x4 acc = {0.f, 0.f, 0.f, 0.f};
            #pragma unroll
            for (int kt = 0; kt < 2; ++kt) {
                acc = MFMA_BF(zh[kt], wh[dt][kt], acc);   // hi*hi
                acc = MFMA_BF(zl[kt], wh[dt][kt], acc);   // lo*hi
                acc = MFMA_BF(zh[kt], wl[dt][kt], acc);   // hi*lo
            }
            #pragma unroll
            for (int r = 0; r < 4; ++r)
                Y[nt*16 + lg*4 + r][dt*16 + l15] = (_Float16)acc[r];
        }
    }
    // single wave: intra-wave lgkmcnt ordering suffices, no barrier

    // ---------------- Phase 2: per-feature tiny MLP (fp16, LDS weights) ---
    const f16x2 zero2 = {(_Float16)0.f, (_Float16)0.f};
    int rb = 0;                       // read buffer  = j % 3
    int sb = 2;                       // stage target = (j+2) % 3

    #pragma unroll 2
    for (int j = 0; j < 32; ++j) {
        // counted wait: stage(j) landed; stage(j+1)'s 3 DMAs stay in flight
        asm volatile("s_waitcnt vmcnt(3)" ::: "memory");
        __builtin_amdgcn_sched_barrier(0);      // rule-18 fence

        const f16x8 ah0 = *(const f16x8*)&Wb[rb][l15*32 + lg*8];
        const f16x8 ah1 = *(const f16x8*)&Wb[rb][(16 + l15)*32 + lg*8];
        H8 w1u, b1u;
        w1u.v = *(const f16x8*)&Tb[rb][lg*4];
        b1u.v = *(const f16x8*)&Tb[rb][16 + lg*4];
        const f32x4 b2a = *(const f32x4*)&Tb[rb][32 + lg*4];   // k2 = lg*4+r
        const f32x4 b2b = *(const f32x4*)&Tb[rb][48 + lg*4];
        const f32x4 w3a = *(const f32x4*)&Tb[rb][64 + lg*4];
        const f32x4 w3b = *(const f32x4*)&Tb[rb][80 + lg*4];
        const float b3v = __uint_as_float(Tb[rb][96]);

        // stage j+2 into the buffer consumed at body j-1 (race-free target)
        stage(dbase + ((j + 2) & 31), sb);      // last 2 iters: dummy restage

        // ---- 4 y reads (f16, conflict-free) ----
        _Float16 yv[4];
        #pragma unroll
        for (int ct = 0; ct < 4; ++ct) yv[ct] = Y[ct*16 + l15][j];

        // ---- 4 independent packed-fp16 layer1 chains ----
        f16x8 pk[4];
        #pragma unroll
        for (int ct = 0; ct < 4; ++ct) {
            const f16x2 y2 = {yv[ct], yv[ct]};
            H8 u;
            #pragma unroll
            for (int q = 0; q < 4; ++q)
                u.h[q] = __builtin_elementwise_max(
                             __builtin_elementwise_fma(y2, w1u.h[q], b1u.h[q]),
                             zero2);
            pk[ct] = u.v;
        }

        // ---- 8 f16 MFMAs (acc init = b2) ----
        f32x4 A0[4], A1[4];
        #pragma unroll
        for (int ct = 0; ct < 4; ++ct) { A0[ct] = b2a; A1[ct] = b2b; }
        #pragma unroll
        for (int ct = 0; ct < 4; ++ct) {
            A0[ct] = MFMA_F16(ah0, pk[ct], A0[ct]);
            A1[ct] = MFMA_F16(ah1, pk[ct], A1[ct]);
        }

        // ---- 4 independent layer3 tails ----
        #pragma unroll
        for (int ct = 0; ct < 4; ++ct) {
            float s = fmaxf(A0[ct][0], 0.f) * w3a[0];
            s = fmaf(fmaxf(A0[ct][1], 0.f), w3a[1], s);
            s = fmaf(fmaxf(A0[ct][2], 0.f), w3a[2], s);
            s = fmaf(fmaxf(A0[ct][3], 0.f), w3a[3], s);
            s = fmaf(fmaxf(A1[ct][0], 0.f), w3b[0], s);
            s = fmaf(fmaxf(A1[ct][1], 0.f), w3b[1], s);
            s = fmaf(fmaxf(A1[ct][2], 0.f), w3b[2], s);
            s = fmaf(fmaxf(A1[ct][3], 0.f), w3b[3], s);
            s += __shfl_xor(s, 16);      // reduce over the 4 lg groups
            s += __shfl_xor(s, 32);
            const float x = fabsf(s + b3v);
            if (lane < 16) Y[ct*16 + lane][j] = (_Float16)x;
        }

        rb = (rb == 2) ? 0 : rb + 1;
        sb = (sb == 2) ? 0 : sb + 1;
    }

    // ---------------- coalesced copy-out (f16 -> f32) ---------------------
    const int cg = lane & 7;
    #pragma unroll
    for (int it = 0; it < 8; ++it) {
        const int n = it*8 + (lane >> 3);
        const f16x4 h = *(const f16x4*)&Y[n][cg*4];
        f32x4 v;
        #pragma unroll
        for (int c = 0; c < 4; ++c) v[c] = (float)h[c];
        *(f32x4*)(out + (size_t)(n0 + n)*128 + dbase + cg*4) = v;
    }
}

extern "C" void kernel_launch(void* const* d_in, const int* in_sizes, int n_in,
                              void* d_out, int out_size, void* d_ws, size_t ws_size,
                              hipStream_t stream) {
    const float* z  = (const float*)d_in[0];
    const float* Wp = (const float*)d_in[1];
    const float* W1 = (const float*)d_in[2];
    const float* b1 = (const float*)d_in[3];
    const float* W2 = (const float*)d_in[4];
    const float* b2 = (const float*)d_in[5];
    const float* W3 = (const float*)d_in[6];
    const float* b3 = (const float*)d_in[7];
    float* out = (float*)d_out;

    __hip_bfloat16* wp_hi = (__hip_bfloat16*)d_ws;          // 8192 B
    __hip_bfloat16* wp_lo = wp_hi + 128 * 64;               // 8192 B
    _Float16*       w2h   = (_Float16*)(wp_lo + 128 * 64);  // 262144 B (linear)
    uint32*         tailp = (uint32*)(w2h + 128 * 1024);    // 57344 B + DMA over-read pad

    hipLaunchKernelGGL(split_weights, dim3(512), dim3(256), 0, stream,
                       Wp, W2, W1, b1, b2, W3, b3, wp_hi, wp_lo, w2h, tailp);
    // 4096 one-wave blocks: bid&3 = feature group, bid>>2 = sample tile
    hipLaunchKernelGGL(decoder_mfma, dim3(4096), dim3(64), 0, stream,
                       z, wp_hi, wp_lo, w2h, tailp, out);
}

// Round 23
// 65.693 us; speedup vs baseline: 1.4172x; 1.4172x over previous
//
#include <hip/hip_runtime.h>
#include <hip/hip_bf16.h>

typedef unsigned int uint32;
typedef __attribute__((ext_vector_type(8))) short    bf16x8;
typedef __attribute__((ext_vector_type(4))) float    f32x4;
typedef __attribute__((ext_vector_type(8))) _Float16 f16x8;
typedef __attribute__((ext_vector_type(4))) _Float16 f16x4;
typedef __attribute__((ext_vector_type(2))) _Float16 f16x2;

#define MFMA_BF(A, B, C) __builtin_amdgcn_mfma_f32_16x16x32_bf16(A, B, C, 0, 0, 0)
#define MFMA_F16(A, B, C) __builtin_amdgcn_mfma_f32_16x16x32_f16(A, B, C, 0, 0, 0)

union FragU { uint32 u[4]; bf16x8 v; };
union H8    { f16x2 h[4]; f16x8 v; };

// 3-pass split (phase-1 z only): hi=trunc top16, lo=bf16(x-hi)
__device__ __forceinline__ void split8(f32x4 a, f32x4 b, bf16x8& hi, bf16x8& lo) {
    float e[8] = {a[0], a[1], a[2], a[3], b[0], b[1], b[2], b[3]};
    FragU H, L;
    #pragma unroll
    for (int q = 0; q < 4; ++q) {
        uint32 u0 = __float_as_uint(e[2*q]);
        uint32 u1 = __float_as_uint(e[2*q + 1]);
        uint32 h0 = u0 & 0xFFFF0000u;
        uint32 h1 = u1 & 0xFFFF0000u;
        float l0 = e[2*q]     - __uint_as_float(h0);
        float l1 = e[2*q + 1] - __uint_as_float(h1);
        H.u[q] = (h0 >> 16) | h1;
        L.u[q] = (__float_as_uint(l0) >> 16) | (__float_as_uint(l1) & 0xFFFF0000u);
    }
    hi = H.v; lo = L.v;
}

// ---- pre-kernel: |Wp| -> bf16 hi/lo; W2 -> fp16; W1,b1 -> packed f16x2 ----
__global__ __launch_bounds__(256) void split_weights(
    const float* __restrict__ Wp, const float* __restrict__ W2,
    const float* __restrict__ W1, const float* __restrict__ b1,
    __hip_bfloat16* __restrict__ wp_hi, __hip_bfloat16* __restrict__ wp_lo,
    _Float16* __restrict__ w2h, f16x2* __restrict__ w1p, f16x2* __restrict__ b1p)
{
    const int i = blockIdx.x * 256 + threadIdx.x;
    if (i < 128 * 64) {
        float x = fabsf(Wp[i]);
        __hip_bfloat16 h = __float2bfloat16(x);          // RNE
        wp_hi[i] = h;
        wp_lo[i] = __float2bfloat16(x - __bfloat162float(h));
    }
    if (i < 128 * 1024) {
        w2h[i] = (_Float16)W2[i];                        // RNE
    }
    if (i < 128 * 16) {
        const int d = i >> 4, q = i & 15;
        f16x2 a, b;
        a[0] = (_Float16)W1[d*32 + 2*q];  a[1] = (_Float16)W1[d*32 + 2*q + 1];
        b[0] = (_Float16)b1[d*32 + 2*q];  b[1] = (_Float16)b1[d*32 + 2*q + 1];
        w1p[i] = a;  b1p[i] = b;
    }
}

// 1 wave per block (r13 structure, proven 65.8us): 64 samples x 32 features.
// Phase 1: Y = z @ |Wp|^T, 3-pass bf16 MFMA -> LDS Y[64][33] f16.
// Phase 2 per j: layer1 in PACKED fp16 (result IS the f16 MFMA B-frag);
//   layer2 = 8x mfma_f32_16x16x32_f16, single-pass fp16 W2, acc init = b2;
//   layer3 scalar f32 + shfl reduce. s_setprio(1) wraps the MFMA cluster
//   (T5/m191: +4-7% for independent-wave structures; our blocks are 1-wave
//   independent like attn, not barrier-lockstep like GEMM).
__global__ __launch_bounds__(64, 4) void decoder_mfma(
    const float* __restrict__ z,
    const __hip_bfloat16* __restrict__ wp_hi, const __hip_bfloat16* __restrict__ wp_lo,
    const _Float16* __restrict__ w2h,
    const f16x2* __restrict__ w1p, const f16x2* __restrict__ b1p,
    const float* __restrict__ b2,
    const float* __restrict__ W3, const float* __restrict__ b3,
    float* __restrict__ out)
{
    __shared__ float Y[64][33];      // 8448 B, +1 pad

    const int lane = threadIdx.x;    // 0..63
    const int l15  = lane & 15;
    const int lg   = lane >> 4;
    const int g    = blockIdx.x & 3;           // feature group: [32g, 32g+32)
    const int n0   = (blockIdx.x >> 2) * 64;   // sample tile

    // ---------------- Phase 1: Y = z @ |Wp|^T -----------------------------
    bf16x8 wh[2][2], wl[2][2];
    #pragma unroll
    for (int dt = 0; dt < 2; ++dt) {
        const int d = g*32 + dt*16 + l15;
        #pragma unroll
        for (int kt = 0; kt < 2; ++kt) {
            const int off = d*64 + kt*32 + lg*8;
            wh[dt][kt] = *(const bf16x8*)(wp_hi + off);
            wl[dt][kt] = *(const bf16x8*)(wp_lo + off);
        }
    }
    #pragma unroll
    for (int nt = 0; nt < 4; ++nt) {
        bf16x8 zh[2], zl[2];
        #pragma unroll
        for (int kt = 0; kt < 2; ++kt) {
            const float* p = z + (size_t)(n0 + nt*16 + l15)*64 + kt*32 + lg*8;
            split8(*(const f32x4*)p, *(const f32x4*)(p + 4), zh[kt], zl[kt]);
        }
        #pragma unroll
        for (int dt = 0; dt < 2; ++dt) {
            f32x4 acc = {0.f, 0.f, 0.f, 0.f};
            #pragma unroll
            for (int kt = 0; kt < 2; ++kt) {
                acc = MFMA_BF(zh[kt], wh[dt][kt], acc);   // hi*hi
                acc = MFMA_BF(zl[kt], wh[dt][kt], acc);   // lo*hi
                acc = MFMA_BF(zh[kt], wl[dt][kt], acc);   // hi*lo
            }
            #pragma unroll
            for (int r = 0; r < 4; ++r)
                Y[nt*16 + lg*4 + r][dt*16 + l15] = acc[r];
        }
    }
    __syncthreads();

    // ---------------- Phase 2: per-feature tiny MLP (fp16 datapath) -------
    const f16x2 zero2 = {(_Float16)0.f, (_Float16)0.f};
    #pragma unroll 4
    for (int j = 0; j < 32; ++j) {
        const int d = g*32 + j;                  // wave-uniform feature
        // A-frags: fp16 W2[d] rows (k2 = l15 and 16+l15), k = h = lg*8+i
        const f16x8 ah0 = *(const f16x8*)(w2h + d*1024 + l15*32 + lg*8);
        const f16x8 ah1 = *(const f16x8*)(w2h + d*1024 + (16 + l15)*32 + lg*8);
        // layer-1 weights: 4 packed f16x2 per lane = one 16B load each
        H8 w1u, b1u;
        w1u.v = *(const f16x8*)(w1p + d*16 + lg*4);
        b1u.v = *(const f16x8*)(b1p + d*16 + lg*4);
        const f32x4 b2a = *(const f32x4*)(b2 + d*32 + lg*4);        // k2 = lg*4+r
        const f32x4 b2b = *(const f32x4*)(b2 + d*32 + 16 + lg*4);
        const f32x4 w3a = *(const f32x4*)(W3 + d*32 + lg*4);
        const f32x4 w3b = *(const f32x4*)(W3 + d*32 + 16 + lg*4);
        const float b3v = b3[d];

        // ---- 4 y reads issued together ----
        float yv[4];
        #pragma unroll
        for (int ct = 0; ct < 4; ++ct) yv[ct] = Y[ct*16 + l15][j];

        // ---- 4 independent packed-fp16 layer1 chains (no pack step) ----
        f16x8 pk[4];
        #pragma unroll
        for (int ct = 0; ct < 4; ++ct) {
            const _Float16 yh = (_Float16)yv[ct];
            const f16x2 y2 = {yh, yh};
            H8 u;
            #pragma unroll
            for (int q = 0; q < 4; ++q)
                u.h[q] = __builtin_elementwise_max(
                             __builtin_elementwise_fma(y2, w1u.h[q], b1u.h[q]),
                             zero2);
            pk[ct] = u.v;
        }

        // ---- 8 f16 MFMAs (acc init = b2), priority-boosted ----
        f32x4 A0[4], A1[4];
        #pragma unroll
        for (int ct = 0; ct < 4; ++ct) { A0[ct] = b2a; A1[ct] = b2b; }
        __builtin_amdgcn_s_setprio(1);
        #pragma unroll
        for (int ct = 0; ct < 4; ++ct) {
            A0[ct] = MFMA_F16(ah0, pk[ct], A0[ct]);
            A1[ct] = MFMA_F16(ah1, pk[ct], A1[ct]);
        }
        __builtin_amdgcn_s_setprio(0);

        // ---- 4 independent layer3 tails ----
        #pragma unroll
        for (int ct = 0; ct < 4; ++ct) {
            float s = fmaxf(A0[ct][0], 0.f) * w3a[0];
            s = fmaf(fmaxf(A0[ct][1], 0.f), w3a[1], s);
            s = fmaf(fmaxf(A0[ct][2], 0.f), w3a[2], s);
            s = fmaf(fmaxf(A0[ct][3], 0.f), w3a[3], s);
            s = fmaf(fmaxf(A1[ct][0], 0.f), w3b[0], s);
            s = fmaf(fmaxf(A1[ct][1], 0.f), w3b[1], s);
            s = fmaf(fmaxf(A1[ct][2], 0.f), w3b[2], s);
            s = fmaf(fmaxf(A1[ct][3], 0.f), w3b[3], s);
            s += __shfl_xor(s, 16);      // reduce over the 4 lg groups
            s += __shfl_xor(s, 32);
            const float x = fabsf(s + b3v);
            if (lane < 16) Y[ct*16 + lane][j] = x;
        }
    }
    __syncthreads();

    // ---------------- coalesced copy-out ----------------------------------
    const int cg = lane & 7;
    #pragma unroll
    for (int it = 0; it < 8; ++it) {
        const int n = it*8 + (lane >> 3);
        f32x4 v;
        #pragma unroll
        for (int c = 0; c < 4; ++c) v[c] = Y[n][cg*4 + c];
        *(f32x4*)(out + (size_t)(n0 + n)*128 + g*32 + cg*4) = v;
    }
}

extern "C" void kernel_launch(void* const* d_in, const int* in_sizes, int n_in,
                              void* d_out, int out_size, void* d_ws, size_t ws_size,
                              hipStream_t stream) {
    const float* z  = (const float*)d_in[0];
    const float* Wp = (const float*)d_in[1];
    const float* W1 = (const float*)d_in[2];
    const float* b1 = (const float*)d_in[3];
    const float* W2 = (const float*)d_in[4];
    const float* b2 = (const float*)d_in[5];
    const float* W3 = (const float*)d_in[6];
    const float* b3 = (const float*)d_in[7];
    float* out = (float*)d_out;

    __hip_bfloat16* wp_hi = (__hip_bfloat16*)d_ws;          // 8192 B
    __hip_bfloat16* wp_lo = wp_hi + 128 * 64;               // 8192 B
    _Float16*       w2h   = (_Float16*)(wp_lo + 128 * 64);  // 262144 B
    f16x2*          w1p   = (f16x2*)(w2h + 128 * 1024);     // 4096 B
    f16x2*          b1p   = w1p + 128 * 16;                 // 4096 B

    hipLaunchKernelGGL(split_weights, dim3(512), dim3(256), 0, stream,
                       Wp, W2, W1, b1, wp_hi, wp_lo, w2h, w1p, b1p);
    // 4096 one-wave blocks: bid&3 = feature group, bid>>2 = sample tile
    hipLaunchKernelGGL(decoder_mfma, dim3(4096), dim3(64), 0, stream,
                       z, wp_hi, wp_lo, w2h, w1p, b1p, b2, W3, b3, out);
}

// Round 25
// 65.668 us; speedup vs baseline: 1.4178x; 1.0004x over previous
//
#include <hip/hip_runtime.h>
#include <hip/hip_bf16.h>

typedef unsigned int uint32;
typedef __attribute__((ext_vector_type(8))) short    bf16x8;
typedef __attribute__((ext_vector_type(4))) float    f32x4;
typedef __attribute__((ext_vector_type(8))) _Float16 f16x8;
typedef __attribute__((ext_vector_type(2))) _Float16 f16x2;

#define MFMA_BF(A, B, C) __builtin_amdgcn_mfma_f32_16x16x32_bf16(A, B, C, 0, 0, 0)
#define MFMA_F16(A, B, C) __builtin_amdgcn_mfma_f32_16x16x32_f16(A, B, C, 0, 0, 0)

union FragU { uint32 u[4]; bf16x8 v; };
union H8    { f16x2 h[4]; f16x8 v; };

// 3-pass split (phase-1 z only): hi=trunc top16, lo=bf16(x-hi)
__device__ __forceinline__ void split8(f32x4 a, f32x4 b, bf16x8& hi, bf16x8& lo) {
    float e[8] = {a[0], a[1], a[2], a[3], b[0], b[1], b[2], b[3]};
    FragU H, L;
    #pragma unroll
    for (int q = 0; q < 4; ++q) {
        uint32 u0 = __float_as_uint(e[2*q]);
        uint32 u1 = __float_as_uint(e[2*q + 1]);
        uint32 h0 = u0 & 0xFFFF0000u;
        uint32 h1 = u1 & 0xFFFF0000u;
        float l0 = e[2*q]     - __uint_as_float(h0);
        float l1 = e[2*q + 1] - __uint_as_float(h1);
        H.u[q] = (h0 >> 16) | h1;
        L.u[q] = (__float_as_uint(l0) >> 16) | (__float_as_uint(l1) & 0xFFFF0000u);
    }
    hi = H.v; lo = L.v;
}

// ---- pre-kernel: |Wp| -> bf16 hi/lo; W2 -> fp16; W1,b1 -> packed f16x2 ----
__global__ __launch_bounds__(256) void split_weights(
    const float* __restrict__ Wp, const float* __restrict__ W2,
    const float* __restrict__ W1, const float* __restrict__ b1,
    __hip_bfloat16* __restrict__ wp_hi, __hip_bfloat16* __restrict__ wp_lo,
    _Float16* __restrict__ w2h, f16x2* __restrict__ w1p, f16x2* __restrict__ b1p)
{
    const int i = blockIdx.x * 256 + threadIdx.x;
    if (i < 128 * 64) {
        float x = fabsf(Wp[i]);
        __hip_bfloat16 h = __float2bfloat16(x);          // RNE
        wp_hi[i] = h;
        wp_lo[i] = __float2bfloat16(x - __bfloat162float(h));
    }
    if (i < 128 * 1024) {
        w2h[i] = (_Float16)W2[i];                        // RNE
    }
    if (i < 128 * 16) {
        const int d = i >> 4, q = i & 15;
        f16x2 a, b;
        a[0] = (_Float16)W1[d*32 + 2*q];  a[1] = (_Float16)W1[d*32 + 2*q + 1];
        b[0] = (_Float16)b1[d*32 + 2*q];  b[1] = (_Float16)b1[d*32 + 2*q + 1];
        w1p[i] = a;  b1p[i] = b;
    }
}

// 1 wave per block (proven 65.7us): 64 samples x 32 features.
// Phase 1: Y = z @ |Wp|^T, 3-pass split bf16 MFMA -> LDS Y[64][33].
// Phase 2 per j: layer1 in PACKED fp16 (result IS the f16 MFMA B-frag, no
//   pack step); layer2 = 8x mfma_f32_16x16x32_f16, single-pass fp16 W2,
//   acc init = b2 (bias folded); layer3 scalar f32 + shfl_xor(16,32) reduce.
// Session ledger: packed-f32 (r6), ILP batching (r7/r8), occupancy moves
// (r9/r14/r15), kernel split (r10/r12), SW prefetch (r11/r16), LDS-DMA
// depth-1/2/3 (r17/r18/r21), setprio (r23), asm prefetch (r24) -- all
// falsified. ~70% latency-stall floor is structural at HIP source level.
__global__ __launch_bounds__(64, 4) void decoder_mfma(
    const float* __restrict__ z,
    const __hip_bfloat16* __restrict__ wp_hi, const __hip_bfloat16* __restrict__ wp_lo,
    const _Float16* __restrict__ w2h,
    const f16x2* __restrict__ w1p, const f16x2* __restrict__ b1p,
    const float* __restrict__ b2,
    const float* __restrict__ W3, const float* __restrict__ b3,
    float* __restrict__ out)
{
    __shared__ float Y[64][33];      // 8448 B, +1 pad

    const int lane = threadIdx.x;    // 0..63
    const int l15  = lane & 15;
    const int lg   = lane >> 4;
    const int g    = blockIdx.x & 3;           // feature group: [32g, 32g+32)
    const int n0   = (blockIdx.x >> 2) * 64;   // sample tile

    // ---------------- Phase 1: Y = z @ |Wp|^T -----------------------------
    bf16x8 wh[2][2], wl[2][2];
    #pragma unroll
    for (int dt = 0; dt < 2; ++dt) {
        const int d = g*32 + dt*16 + l15;
        #pragma unroll
        for (int kt = 0; kt < 2; ++kt) {
            const int off = d*64 + kt*32 + lg*8;
            wh[dt][kt] = *(const bf16x8*)(wp_hi + off);
            wl[dt][kt] = *(const bf16x8*)(wp_lo + off);
        }
    }
    #pragma unroll
    for (int nt = 0; nt < 4; ++nt) {
        bf16x8 zh[2], zl[2];
        #pragma unroll
        for (int kt = 0; kt < 2; ++kt) {
            const float* p = z + (size_t)(n0 + nt*16 + l15)*64 + kt*32 + lg*8;
            split8(*(const f32x4*)p, *(const f32x4*)(p + 4), zh[kt], zl[kt]);
        }
        #pragma unroll
        for (int dt = 0; dt < 2; ++dt) {
            f32x4 acc = {0.f, 0.f, 0.f, 0.f};
            #pragma unroll
            for (int kt = 0; kt < 2; ++kt) {
                acc = MFMA_BF(zh[kt], wh[dt][kt], acc);   // hi*hi
                acc = MFMA_BF(zl[kt], wh[dt][kt], acc);   // lo*hi
                acc = MFMA_BF(zh[kt], wl[dt][kt], acc);   // hi*lo
            }
            #pragma unroll
            for (int r = 0; r < 4; ++r)
                Y[nt*16 + lg*4 + r][dt*16 + l15] = acc[r];
        }
    }
    __syncthreads();

    // ---------------- Phase 2: per-feature tiny MLP (fp16 datapath) -------
    const f16x2 zero2 = {(_Float16)0.f, (_Float16)0.f};
    #pragma unroll 4
    for (int j = 0; j < 32; ++j) {
        const int d = g*32 + j;                  // wave-uniform feature
        // A-frags: fp16 W2[d] rows (k2 = l15 and 16+l15), k = h = lg*8+i
        const f16x8 ah0 = *(const f16x8*)(w2h + d*1024 + l15*32 + lg*8);
        const f16x8 ah1 = *(const f16x8*)(w2h + d*1024 + (16 + l15)*32 + lg*8);
        // layer-1 weights: 4 packed f16x2 per lane = one 16B load each
        H8 w1u, b1u;
        w1u.v = *(const f16x8*)(w1p + d*16 + lg*4);
        b1u.v = *(const f16x8*)(b1p + d*16 + lg*4);
        const f32x4 b2a = *(const f32x4*)(b2 + d*32 + lg*4);        // k2 = lg*4+r
        const f32x4 b2b = *(const f32x4*)(b2 + d*32 + 16 + lg*4);
        const f32x4 w3a = *(const f32x4*)(W3 + d*32 + lg*4);
        const f32x4 w3b = *(const f32x4*)(W3 + d*32 + 16 + lg*4);
        const float b3v = b3[d];

        // ---- 4 y reads issued together ----
        float yv[4];
        #pragma unroll
        for (int ct = 0; ct < 4; ++ct) yv[ct] = Y[ct*16 + l15][j];

        // ---- 4 independent packed-fp16 layer1 chains (no pack step) ----
        f16x8 pk[4];
        #pragma unroll
        for (int ct = 0; ct < 4; ++ct) {
            const _Float16 yh = (_Float16)yv[ct];
            const f16x2 y2 = {yh, yh};
            H8 u;
            #pragma unroll
            for (int q = 0; q < 4; ++q)
                u.h[q] = __builtin_elementwise_max(
                             __builtin_elementwise_fma(y2, w1u.h[q], b1u.h[q]),
                             zero2);
            pk[ct] = u.v;
        }

        // ---- 8 f16 MFMAs (acc init = b2) ----
        f32x4 A0[4], A1[4];
        #pragma unroll
        for (int ct = 0; ct < 4; ++ct) { A0[ct] = b2a; A1[ct] = b2b; }
        #pragma unroll
        for (int ct = 0; ct < 4; ++ct) {
            A0[ct] = MFMA_F16(ah0, pk[ct], A0[ct]);
            A1[ct] = MFMA_F16(ah1, pk[ct], A1[ct]);
        }

        // ---- 4 independent layer3 tails ----
        #pragma unroll
        for (int ct = 0; ct < 4; ++ct) {
            float s = fmaxf(A0[ct][0], 0.f) * w3a[0];
            s = fmaf(fmaxf(A0[ct][1], 0.f), w3a[1], s);
            s = fmaf(fmaxf(A0[ct][2], 0.f), w3a[2], s);
            s = fmaf(fmaxf(A0[ct][3], 0.f), w3a[3], s);
            s = fmaf(fmaxf(A1[ct][0], 0.f), w3b[0], s);
            s = fmaf(fmaxf(A1[ct][1], 0.f), w3b[1], s);
            s = fmaf(fmaxf(A1[ct][2], 0.f), w3b[2], s);
            s = fmaf(fmaxf(A1[ct][3], 0.f), w3b[3], s);
            s += __shfl_xor(s, 16);      // reduce over the 4 lg groups
            s += __shfl_xor(s, 32);
            const float x = fabsf(s + b3v);
            if (lane < 16) Y[ct*16 + lane][j] = x;
        }
    }
    __syncthreads();

    // ---------------- coalesced copy-out ----------------------------------
    const int cg = lane & 7;
    #pragma unroll
    for (int it = 0; it < 8; ++it) {
        const int n = it*8 + (lane >> 3);
        f32x4 v;
        #pragma unroll
        for (int c = 0; c < 4; ++c) v[c] = Y[n][cg*4 + c];
        *(f32x4*)(out + (size_t)(n0 + n)*128 + g*32 + cg*4) = v;
    }
}

extern "C" void kernel_launch(void* const* d_in, const int* in_sizes, int n_in,
                              void* d_out, int out_size, void* d_ws, size_t ws_size,
                              hipStream_t stream) {
    const float* z  = (const float*)d_in[0];
    const float* Wp = (const float*)d_in[1];
    const float* W1 = (const float*)d_in[2];
    const float* b1 = (const float*)d_in[3];
    const float* W2 = (const float*)d_in[4];
    const float* b2 = (const float*)d_in[5];
    const float* W3 = (const float*)d_in[6];
    const float* b3 = (const float*)d_in[7];
    float* out = (float*)d_out;

    __hip_bfloat16* wp_hi = (__hip_bfloat16*)d_ws;          // 8192 B
    __hip_bfloat16* wp_lo = wp_hi + 128 * 64;               // 8192 B
    _Float16*       w2h   = (_Float16*)(wp_lo + 128 * 64);  // 262144 B
    f16x2*          w1p   = (f16x2*)(w2h + 128 * 1024);     // 4096 B
    f16x2*          b1p   = w1p + 128 * 16;                 // 4096 B

    hipLaunchKernelGGL(split_weights, dim3(512), dim3(256), 0, stream,
                       Wp, W2, W1, b1, wp_hi, wp_lo, w2h, w1p, b1p);
    // 4096 one-wave blocks: bid&3 = feature group, bid>>2 = sample tile
    hipLaunchKernelGGL(decoder_mfma, dim3(4096), dim3(64), 0, stream,
                       z, wp_hi, wp_lo, w2h, w1p, b1p, b2, W3, b3, out);
}